// Round 10
// baseline (93.410 us; speedup 1.0000x reference)
//
#include <hip/hip_runtime.h>
#include <hip/hip_bf16.h>

// MultiLinear: y[b,g,o] = sum_i x[b,g,i] * W[g,o,i] + bias[g,o]
// B=4096, G=16, DIN=512, DOUT=512, fp32 in/out.
// R10: occupancy via SMALL ACCUMULATOR. 128x256 tile (BN=256 keeps X-traffic
// minimal: DOUT/BN=2), BK=32, 8 waves (2m x 4n), wave-tile 64x64 -> acc 64
// AGPR. Total regs pinned to 128 (launch_bounds(512,4)) -> 2 independent
// blocks/CU (16 waves): the other block fills barrier/latency bubbles that
// kept R4-R9 at <15% MfmaUtil with 1 lockstep block/CU.
// B staged via global_load_lds DMA from bf16 prepass (T21: linear LDS dest +
// rotated-chunk global src + rotated read). A reg-staged distance-1 + cvt.

#define BATCH 4096
#define NGRP  16
#define DIN   512
#define DOUT  512

#define BM 128
#define BN 256
#define BK 32
#define NT (DIN / BK)   // 16 K-steps
#define LDKA 40         // A pad: 80 B row stride (5 x 16B units, coprime 8)

typedef __bf16 bf16x8 __attribute__((ext_vector_type(8)));
typedef float  f32x4  __attribute__((ext_vector_type(4)));
typedef const __attribute__((address_space(1))) void gas_void;
typedef __attribute__((address_space(3))) void las_void;

// ---------- prepass: W fp32 -> bf16 into d_ws (canonical layout) ----------
__global__ __launch_bounds__(256)
void wcvt_kernel(const float* __restrict__ W, __bf16* __restrict__ Wb) {
    const int i = (blockIdx.x * 256 + threadIdx.x) * 8;
    f32x4 a = *(const f32x4*)(W + i);
    f32x4 b = *(const f32x4*)(W + i + 4);
    bf16x8 v;
#pragma unroll
    for (int j = 0; j < 4; ++j) { v[j] = (__bf16)a[j]; v[j + 4] = (__bf16)b[j]; }
    *(bf16x8*)(Wb + i) = v;
}

// ---------- main GEMM ----------
__global__ __launch_bounds__(512, 4)
void MultiLinear_48498770706571_kernel(const float* __restrict__ X,
                                       const __bf16* __restrict__ Wb,
                                       const float* __restrict__ Bias,
                                       float* __restrict__ Y) {
    // 1024 blocks / 8 XCDs = 128 consecutive tiles (2 full groups) per XCD.
    const int bid = (blockIdx.x & 7) * 128 + (blockIdx.x >> 3);
    const int g   = bid >> 6;          // 64 tiles per group (32 m x 2 n)
    const int mt  = (bid >> 1) & 31;
    const int nt  = bid & 1;
    const int bm0 = mt * BM;
    const int bn0 = nt * BN;

    __shared__ __bf16 As[2][BM][LDKA];    // 20 KB, reg-staged + cvt
    __shared__ __bf16 BsF[2][BN * BK];    // 32 KB, linear, DMA-filled

    const int tid  = threadIdx.x;
    const int lane = tid & 63;
    const int w    = tid >> 6;        // 0..7
    const int wm   = (w >> 2) * 64;   // {0,64}
    const int wn   = (w & 3) * 64;    // {0,64,128,192}
    const int l15  = lane & 15;
    const int kq   = (lane >> 4) * 8; // 0,8,16,24

    // A staging: 4 thr/row, 8 floats each; 128 rows by 512 threads.
    const int srow = tid >> 2;        // 0..127
    const int scol = (tid & 3) * 8;   // 0,8,16,24
    const float* pA = X + (size_t)(bm0 + srow) * (NGRP * DIN) + g * DIN + scol;

    // B DMA geometry: wave w covers rows w*32..+31; 2 issues of 1 KB each.
    // Chunk rotation: LDS[row][pos] holds global chunk (pos - (row>>1)) & 3.
    const __bf16* wbase = Wb + (size_t)g * (DOUT * DIN) + (size_t)bn0 * DIN;
    const int rowg0 = (w << 5) + (lane >> 2);   // + q*16
    const int posd  = lane & 3;

    f32x4 ra[2];   // 8 VGPRs in flight (A only; B is DMA)

#define ISSUE_A(k0)                                                        \
    do {                                                                   \
        const f32x4* qa = (const f32x4*)(pA + (k0));                       \
        ra[0] = qa[0]; ra[1] = qa[1];                                      \
    } while (0)

#define CVT_WRITE_A(buf)                                                   \
    do {                                                                   \
        bf16x8 v;                                                          \
        _Pragma("unroll")                                                  \
        for (int j = 0; j < 4; ++j) {                                      \
            v[j] = (__bf16)ra[0][j]; v[j + 4] = (__bf16)ra[1][j];          \
        }                                                                  \
        *(bf16x8*)&As[buf][srow][scol] = v;                                \
    } while (0)

#define DMA_B(kt, buf)                                                     \
    do {                                                                   \
        _Pragma("unroll")                                                  \
        for (int q = 0; q < 2; ++q) {                                      \
            const int rowg = rowg0 + (q << 4);                             \
            const int csrc = (posd + 4 - ((rowg >> 1) & 3)) & 3;           \
            const __bf16* gp = wbase + (size_t)rowg * DIN + (kt) * BK      \
                               + (csrc << 3);                              \
            __builtin_amdgcn_global_load_lds(                              \
                (gas_void*)gp,                                             \
                (las_void*)&BsF[buf][(w << 10) + (q << 9)], 16, 0, 0);     \
        }                                                                  \
    } while (0)

#define COMPUTE(buf)                                                       \
    do {                                                                   \
        bf16x8 af[4], bfr[4];                                              \
        _Pragma("unroll")                                                  \
        for (int mi = 0; mi < 4; ++mi)                                     \
            af[mi] = *(const bf16x8*)&As[buf][wm + mi * 16 + l15][kq];     \
        _Pragma("unroll")                                                  \
        for (int ni = 0; ni < 4; ++ni) {                                   \
            const int brow = wn + ni * 16 + l15;                           \
            const int pos = ((lane >> 4) + ((brow >> 1) & 3)) & 3;         \
            bfr[ni] = *(const bf16x8*)&BsF[buf][brow * 32 + (pos << 3)];   \
        }                                                                  \
        _Pragma("unroll")                                                  \
        for (int mi = 0; mi < 4; ++mi)                                     \
            _Pragma("unroll")                                              \
            for (int ni = 0; ni < 4; ++ni)                                 \
                acc[mi][ni] = __builtin_amdgcn_mfma_f32_16x16x32_bf16(     \
                    af[mi], bfr[ni], acc[mi][ni], 0, 0, 0);                \
    } while (0)

    f32x4 acc[4][4];
#pragma unroll
    for (int mi = 0; mi < 4; ++mi)
#pragma unroll
        for (int ni = 0; ni < 4; ++ni) acc[mi][ni] = f32x4{0.f, 0.f, 0.f, 0.f};

    // prologue: A(0) + DMA B(0) into buf0; write A(0); prefetch A(1).
    ISSUE_A(0);
    DMA_B(0, 0);
    CVT_WRITE_A(0);      // drains ra(0); DMA(0) stays in flight (newer? no:
                         // A issued first -> compiler waits vmcnt(2), DMA ok)
    ISSUE_A(BK);

    for (int kt = 0; kt < NT; ++kt) {
        const int cur = kt & 1;
        // Drain DMA(kt): outstanding = DMA(kt)[2 oldest] + ra(kt+1)[2 newer].
        if (kt + 1 < NT)
            asm volatile("s_waitcnt vmcnt(2)" ::: "memory");
        else
            asm volatile("s_waitcnt vmcnt(0)" ::: "memory");
        asm volatile("s_waitcnt lgkmcnt(0)" ::: "memory");
        __builtin_amdgcn_s_barrier();

        // buf cur^1 readers all drained before barrier -> WAR-safe refill.
        if (kt + 1 < NT) DMA_B(kt + 1, cur ^ 1);

        COMPUTE(cur);

        if (kt + 1 < NT) {
            CVT_WRITE_A(cur ^ 1);            // vmcnt(2): waits ra, not DMA
            if (kt + 2 < NT) ISSUE_A((kt + 2) * BK);
        }
    }

    // epilogue: C/D layout col = lane&15, row = (lane>>4)*4 + j (verified R1)
    const int r0 = (lane >> 4) * 4;
    const int c  = lane & 15;
    float bias_n[4];
#pragma unroll
    for (int ni = 0; ni < 4; ++ni)
        bias_n[ni] = Bias[g * DOUT + bn0 + wn + ni * 16 + c];
#pragma unroll
    for (int mi = 0; mi < 4; ++mi) {
#pragma unroll
        for (int j = 0; j < 4; ++j) {
            const int row = bm0 + wm + mi * 16 + r0 + j;
            float* yrow = Y + (size_t)row * (NGRP * DOUT) + g * DOUT + bn0 + wn;
#pragma unroll
            for (int ni = 0; ni < 4; ++ni)
                yrow[ni * 16 + c] = acc[mi][ni][j] + bias_n[ni];
        }
    }
#undef ISSUE_A
#undef CVT_WRITE_A
#undef DMA_B
#undef COMPUTE
}

extern "C" void kernel_launch(void* const* d_in, const int* in_sizes, int n_in,
                              void* d_out, int out_size, void* d_ws, size_t ws_size,
                              hipStream_t stream) {
    const float* X    = (const float*)d_in[0];
    const float* W    = (const float*)d_in[1];
    const float* Bias = (const float*)d_in[2];
    float* Y          = (float*)d_out;
    __bf16* Wb        = (__bf16*)d_ws;   // 8 MB scratch

    // prepass: 16*512*512 = 4M elems / (256 thr * 8 elems) = 2048 blocks
    wcvt_kernel<<<2048, 256, 0, stream>>>(W, Wb);

    const int grid = NGRP * (BATCH / BM) * (DOUT / BN);  // 16*32*2 = 1024
    MultiLinear_48498770706571_kernel<<<grid, 512, 0, stream>>>(X, Wb, Bias, Y);
}